// Round 1
// baseline (93.372 us; speedup 1.0000x reference)
//
#include <hip/hip_runtime.h>
#include <hip/hip_bf16.h>
#include <math.h>

#define BB 32
#define SS 256
#define DD 128
#define KK 16
#define SK (SS*KK)   // 4096

typedef __attribute__((ext_vector_type(8))) short bf16x8;
typedef __attribute__((ext_vector_type(4))) float f32x4;

static __device__ __forceinline__ short f2bf(float f) {
    unsigned u = __float_as_uint(f);
    unsigned r = (u + 0x7fffu + ((u >> 16) & 1u)) >> 16;
    return (short)r;
}

// byte offset of element (row, d) in a [64][128] bf16 LDS tile, XOR-swizzled
static __device__ __forceinline__ int lds_off(int row, int d) {
    return row * 256 + ((d * 2) ^ ((row & 7) << 4));
}

__global__ __launch_bounds__(256)
void neg_loss_kernel(const float* __restrict__ latent,   // [B,S,D]
                     const int*   __restrict__ labels,   // [B,S]
                     const int*   __restrict__ samples,  // [B,S*(K-1)]
                     const float* __restrict__ embed,    // [V,D]
                     float* __restrict__ out)            // [B,S,S]
{
    __shared__ char ldsA[64 * 256];
    __shared__ char ldsB[64 * 256];

    const int b   = blockIdx.z;
    const int m0  = blockIdx.y * 64;
    const int n0  = blockIdx.x * 64;
    const int tid = threadIdx.x;

    // ---- stage A: latent rows -> bf16 LDS (swizzled) ----
    {
        const int r  = tid >> 2;          // 0..63
        const int d0 = (tid & 3) * 32;    // 0,32,64,96
        const float* src = latent + ((size_t)b * SS + (m0 + r)) * DD + d0;
        float f[32];
        #pragma unroll
        for (int c = 0; c < 8; ++c)
            *(float4*)(f + 4 * c) = ((const float4*)src)[c];
        #pragma unroll
        for (int c = 0; c < 4; ++c) {
            short tmp[8];
            #pragma unroll
            for (int e = 0; e < 8; ++e) tmp[e] = f2bf(f[c * 8 + e]);
            *(bf16x8*)(ldsA + lds_off(r, d0 + c * 8)) = *(bf16x8*)tmp;
        }
    }

    // ---- stage B: gathered embeddings -> bf16 LDS (swizzled) ----
    {
        const int c   = tid >> 2;         // column in tile, 0..63
        const int d0  = (tid & 3) * 32;
        const int col = n0 + c;           // global column 0..4095
        const int j   = col >> 4;
        const int k   = col & 15;
        const int idx = (k < 15) ? samples[(size_t)b * (SS * (KK - 1)) + j * (KK - 1) + k]
                                 : labels[b * SS + j];
        const float* src = embed + (size_t)idx * DD + d0;
        float f[32];
        #pragma unroll
        for (int cc = 0; cc < 8; ++cc)
            *(float4*)(f + 4 * cc) = ((const float4*)src)[cc];
        #pragma unroll
        for (int cc = 0; cc < 4; ++cc) {
            short tmp[8];
            #pragma unroll
            for (int e = 0; e < 8; ++e) tmp[e] = f2bf(f[cc * 8 + e]);
            *(bf16x8*)(ldsB + lds_off(c, d0 + cc * 8)) = *(bf16x8*)tmp;
        }
    }

    __syncthreads();

    // ---- MFMA compute: each wave does a 32x32 subtile ----
    const int wave = tid >> 6;
    const int lane = tid & 63;
    const int wm = wave >> 1, wn = wave & 1;
    const int lr = lane & 15;
    const int lk = (lane >> 4) * 8;

    f32x4 acc[2][2] = {};
    #pragma unroll
    for (int ks = 0; ks < 4; ++ks) {
        const int d = ks * 32 + lk;
        bf16x8 a[2], bb[2];
        #pragma unroll
        for (int mf = 0; mf < 2; ++mf) {
            const int r = wm * 32 + mf * 16 + lr;
            a[mf] = *(const bf16x8*)(ldsA + lds_off(r, d));
        }
        #pragma unroll
        for (int nf = 0; nf < 2; ++nf) {
            const int cc = wn * 32 + nf * 16 + lr;
            bb[nf] = *(const bf16x8*)(ldsB + lds_off(cc, d));
        }
        #pragma unroll
        for (int mf = 0; mf < 2; ++mf)
            #pragma unroll
            for (int nf = 0; nf < 2; ++nf)
                acc[mf][nf] = __builtin_amdgcn_mfma_f32_16x16x32_bf16(
                    a[mf], bb[nf], acc[mf][nf], 0, 0, 0);
    }

    // ---- fused LSE epilogue ----
    // C frag layout: col = lane&15 (the k within a j-group), row = (lane>>4)*4 + reg
    #pragma unroll
    for (int mf = 0; mf < 2; ++mf) {
        #pragma unroll
        for (int nf = 0; nf < 2; ++nf) {
            const f32x4 v = acc[mf][nf];
            const int jj = (n0 >> 4) + wn * 2 + nf;   // global j
            #pragma unroll
            for (int r = 0; r < 4; ++r) {
                float x = v[r];
                float pos = __shfl(x, (lane & 48) | 15);   // k==15 column
                float m = x;
                m = fmaxf(m, __shfl_xor(m, 1));
                m = fmaxf(m, __shfl_xor(m, 2));
                m = fmaxf(m, __shfl_xor(m, 4));
                m = fmaxf(m, __shfl_xor(m, 8));
                float e = __expf(x - m);
                e += __shfl_xor(e, 1);
                e += __shfl_xor(e, 2);
                e += __shfl_xor(e, 4);
                e += __shfl_xor(e, 8);
                if ((lane & 15) == 0) {
                    const int i = m0 + wm * 32 + mf * 16 + (lane >> 4) * 4 + r;
                    out[((size_t)b * SS + i) * SS + jj] = pos - m - __logf(e);
                }
            }
        }
    }
}

extern "C" void kernel_launch(void* const* d_in, const int* in_sizes, int n_in,
                              void* d_out, int out_size, void* d_ws, size_t ws_size,
                              hipStream_t stream) {
    const float* latent  = (const float*)d_in[0];
    const int*   labels  = (const int*)d_in[1];
    const int*   samples = (const int*)d_in[2];
    const float* embed   = (const float*)d_in[3];
    float* out = (float*)d_out;

    dim3 grid(SK / 64, SS / 64, BB);
    neg_loss_kernel<<<grid, dim3(256), 0, stream>>>(latent, labels, samples, embed, out);
}

// Round 2
// 93.086 us; speedup vs baseline: 1.0031x; 1.0031x over previous
//
#include <hip/hip_runtime.h>
#include <hip/hip_bf16.h>
#include <math.h>

#define BB 32
#define SS 256
#define DD 128
#define KK 16
#define VV 50000
#define SK (SS*KK)   // 4096

typedef __attribute__((ext_vector_type(8))) short bf16x8;
typedef __attribute__((ext_vector_type(4))) float f32x4;
typedef unsigned short ushort_t;

static __device__ __forceinline__ short f2bf(float f) {
    unsigned u = __float_as_uint(f);
    unsigned r = (u + 0x7fffu + ((u >> 16) & 1u)) >> 16;
    return (short)r;
}

// byte offset of element (row, d) in a [R][128] bf16 LDS tile, XOR-swizzled
// (16B chunk index q -> q ^ (row&7))
static __device__ __forceinline__ int lds_off(int row, int d) {
    return row * 256 + ((d * 2) ^ ((row & 7) << 4));
}

static __device__ __forceinline__ void gload_lds16(const void* g, void* lds) {
    __builtin_amdgcn_global_load_lds(
        (const __attribute__((address_space(1))) unsigned int*)g,
        (__attribute__((address_space(3))) unsigned int*)lds, 16, 0, 0);
}

// ---------------- convert kernel: fp32 -> bf16 (embed then latent) ----------
#define NEMB (VV*DD)          // 6,400,000
#define NLAT (BB*SS*DD)       // 1,048,576
#define NCHUNK ((NEMB+NLAT)/8) // 931,072

__global__ __launch_bounds__(256)
void convert_kernel(const float* __restrict__ embed,
                    const float* __restrict__ latent,
                    ushort_t* __restrict__ ws_emb,
                    ushort_t* __restrict__ ws_lat)
{
    int i = blockIdx.x * 256 + threadIdx.x;
    if (i >= NCHUNK) return;
    const float* src;
    ushort_t* dst;
    if (i < NEMB / 8) {
        src = embed + (size_t)i * 8;
        dst = ws_emb + (size_t)i * 8;
    } else {
        int k = i - NEMB / 8;
        src = latent + (size_t)k * 8;
        dst = ws_lat + (size_t)k * 8;
    }
    float f[8];
    *(float4*)(f + 0) = ((const float4*)src)[0];
    *(float4*)(f + 4) = ((const float4*)src)[1];
    short o[8];
    #pragma unroll
    for (int e = 0; e < 8; ++e) o[e] = f2bf(f[e]);
    *(bf16x8*)dst = *(bf16x8*)o;
}

// ---------------- main kernel: 64x128 tile, bf16 inputs via ws --------------
#define MT 64
#define NT 128

__global__ __launch_bounds__(256)
void neg_loss_main(const ushort_t* __restrict__ lat_bf,   // [B,S,D] bf16
                   const int*      __restrict__ labels,   // [B,S]
                   const int*      __restrict__ samples,  // [B,S*(K-1)]
                   const ushort_t* __restrict__ emb_bf,   // [V,D] bf16
                   float* __restrict__ out)               // [B,S,S]
{
    __shared__ char ldsA[MT * 256];   // 16 KB
    __shared__ char ldsB[NT * 256];   // 32 KB

    const int b    = blockIdx.z;
    const int m0   = blockIdx.y * MT;
    const int n0   = blockIdx.x * NT;
    const int tid  = threadIdx.x;
    const int wave = tid >> 6;
    const int lane = tid & 63;
    const int q    = lane & 15;
    const int sub  = lane >> 4;   // 0..3

    // ---- stage A: 64 latent rows (bf16), src pre-swizzled, LDS linear ----
    #pragma unroll
    for (int t = 0; t < 4; ++t) {
        const int r0 = wave * 16 + t * 4;
        const int r  = r0 + sub;
        const ushort_t* src = lat_bf + ((size_t)(b * SS + m0 + r) * DD)
                                     + ((q ^ (r & 7)) << 3);
        gload_lds16(src, ldsA + r0 * 256);
    }

    // ---- stage B: 128 gathered embedding rows (bf16) ----
    #pragma unroll
    for (int t = 0; t < 8; ++t) {
        const int c0 = wave * 32 + t * 4;
        const int c  = c0 + sub;
        const int gc = n0 + c;
        const int j  = gc >> 4;
        const int k  = gc & 15;
        const int idx = (k < 15)
            ? samples[(size_t)b * (SS * (KK - 1)) + j * (KK - 1) + k]
            : labels[b * SS + j];
        const ushort_t* src = emb_bf + (size_t)idx * DD + ((q ^ (c & 7)) << 3);
        gload_lds16(src, ldsB + c0 * 256);
    }

    __syncthreads();

    // ---- MFMA: wave w computes rows 0..63 x cols [w*32, w*32+32) ----
    const int lr = lane & 15;
    const int lk = (lane >> 4) * 8;

    f32x4 acc[4][2] = {};
    #pragma unroll
    for (int ks = 0; ks < 4; ++ks) {
        const int d = ks * 32 + lk;
        bf16x8 a[4], bv[2];
        #pragma unroll
        for (int mf = 0; mf < 4; ++mf)
            a[mf] = *(const bf16x8*)(ldsA + lds_off(mf * 16 + lr, d));
        #pragma unroll
        for (int nf = 0; nf < 2; ++nf)
            bv[nf] = *(const bf16x8*)(ldsB + lds_off(wave * 32 + nf * 16 + lr, d));
        #pragma unroll
        for (int mf = 0; mf < 4; ++mf)
            #pragma unroll
            for (int nf = 0; nf < 2; ++nf)
                acc[mf][nf] = __builtin_amdgcn_mfma_f32_16x16x32_bf16(
                    a[mf], bv[nf], acc[mf][nf], 0, 0, 0);
    }

    // ---- fused LSE epilogue ----
    // C frag layout: col(k) = lane&15, row = (lane>>4)*4 + reg
    #pragma unroll
    for (int mf = 0; mf < 4; ++mf) {
        #pragma unroll
        for (int nf = 0; nf < 2; ++nf) {
            const f32x4 v = acc[mf][nf];
            const int jj = (n0 >> 4) + wave * 2 + nf;
            #pragma unroll
            for (int r = 0; r < 4; ++r) {
                float x = v[r];
                float pos = __shfl(x, (lane & 48) | 15);   // k==15 column
                float m = x;
                m = fmaxf(m, __shfl_xor(m, 1));
                m = fmaxf(m, __shfl_xor(m, 2));
                m = fmaxf(m, __shfl_xor(m, 4));
                m = fmaxf(m, __shfl_xor(m, 8));
                float e = __expf(x - m);
                e += __shfl_xor(e, 1);
                e += __shfl_xor(e, 2);
                e += __shfl_xor(e, 4);
                e += __shfl_xor(e, 8);
                if ((lane & 15) == 0) {
                    const int i = m0 + mf * 16 + sub * 4 + r;
                    out[((size_t)b * SS + i) * SS + jj] = pos - m - __logf(e);
                }
            }
        }
    }
}

// ---------------- fallback (R1 kernel, fp32 gather + in-kernel convert) -----
__global__ __launch_bounds__(256)
void neg_loss_fallback(const float* __restrict__ latent,
                       const int*   __restrict__ labels,
                       const int*   __restrict__ samples,
                       const float* __restrict__ embed,
                       float* __restrict__ out)
{
    __shared__ char ldsA[64 * 256];
    __shared__ char ldsB[64 * 256];

    const int b   = blockIdx.z;
    const int m0  = blockIdx.y * 64;
    const int n0  = blockIdx.x * 64;
    const int tid = threadIdx.x;

    {
        const int r  = tid >> 2;
        const int d0 = (tid & 3) * 32;
        const float* src = latent + ((size_t)b * SS + (m0 + r)) * DD + d0;
        float f[32];
        #pragma unroll
        for (int c = 0; c < 8; ++c)
            *(float4*)(f + 4 * c) = ((const float4*)src)[c];
        #pragma unroll
        for (int c = 0; c < 4; ++c) {
            short tmp[8];
            #pragma unroll
            for (int e = 0; e < 8; ++e) tmp[e] = f2bf(f[c * 8 + e]);
            *(bf16x8*)(ldsA + lds_off(r, d0 + c * 8)) = *(bf16x8*)tmp;
        }
    }
    {
        const int c   = tid >> 2;
        const int d0  = (tid & 3) * 32;
        const int col = n0 + c;
        const int j   = col >> 4;
        const int k   = col & 15;
        const int idx = (k < 15) ? samples[(size_t)b * (SS * (KK - 1)) + j * (KK - 1) + k]
                                 : labels[b * SS + j];
        const float* src = embed + (size_t)idx * DD + d0;
        float f[32];
        #pragma unroll
        for (int cc = 0; cc < 8; ++cc)
            *(float4*)(f + 4 * cc) = ((const float4*)src)[cc];
        #pragma unroll
        for (int cc = 0; cc < 4; ++cc) {
            short tmp[8];
            #pragma unroll
            for (int e = 0; e < 8; ++e) tmp[e] = f2bf(f[cc * 8 + e]);
            *(bf16x8*)(ldsB + lds_off(c, d0 + cc * 8)) = *(bf16x8*)tmp;
        }
    }
    __syncthreads();

    const int wave = tid >> 6;
    const int lane = tid & 63;
    const int wm = wave >> 1, wn = wave & 1;
    const int lr = lane & 15;
    const int lk = (lane >> 4) * 8;

    f32x4 acc[2][2] = {};
    #pragma unroll
    for (int ks = 0; ks < 4; ++ks) {
        const int d = ks * 32 + lk;
        bf16x8 a[2], bb2[2];
        #pragma unroll
        for (int mf = 0; mf < 2; ++mf)
            a[mf] = *(const bf16x8*)(ldsA + lds_off(wm * 32 + mf * 16 + lr, d));
        #pragma unroll
        for (int nf = 0; nf < 2; ++nf)
            bb2[nf] = *(const bf16x8*)(ldsB + lds_off(wn * 32 + nf * 16 + lr, d));
        #pragma unroll
        for (int mf = 0; mf < 2; ++mf)
            #pragma unroll
            for (int nf = 0; nf < 2; ++nf)
                acc[mf][nf] = __builtin_amdgcn_mfma_f32_16x16x32_bf16(
                    a[mf], bb2[nf], acc[mf][nf], 0, 0, 0);
    }

    #pragma unroll
    for (int mf = 0; mf < 2; ++mf) {
        #pragma unroll
        for (int nf = 0; nf < 2; ++nf) {
            const f32x4 v = acc[mf][nf];
            const int jj = (n0 >> 4) + wn * 2 + nf;
            #pragma unroll
            for (int r = 0; r < 4; ++r) {
                float x = v[r];
                float pos = __shfl(x, (lane & 48) | 15);
                float m = x;
                m = fmaxf(m, __shfl_xor(m, 1));
                m = fmaxf(m, __shfl_xor(m, 2));
                m = fmaxf(m, __shfl_xor(m, 4));
                m = fmaxf(m, __shfl_xor(m, 8));
                float e = __expf(x - m);
                e += __shfl_xor(e, 1);
                e += __shfl_xor(e, 2);
                e += __shfl_xor(e, 4);
                e += __shfl_xor(e, 8);
                if ((lane & 15) == 0) {
                    const int i = m0 + wm * 32 + mf * 16 + (lane >> 4) * 4 + r;
                    out[((size_t)b * SS + i) * SS + jj] = pos - m - __logf(e);
                }
            }
        }
    }
}

extern "C" void kernel_launch(void* const* d_in, const int* in_sizes, int n_in,
                              void* d_out, int out_size, void* d_ws, size_t ws_size,
                              hipStream_t stream) {
    const float* latent  = (const float*)d_in[0];
    const int*   labels  = (const int*)d_in[1];
    const int*   samples = (const int*)d_in[2];
    const float* embed   = (const float*)d_in[3];
    float* out = (float*)d_out;

    const size_t ws_needed = (size_t)(NEMB + NLAT) * 2;
    if (ws_size >= ws_needed) {
        ushort_t* ws_emb = (ushort_t*)d_ws;
        ushort_t* ws_lat = ws_emb + NEMB;
        convert_kernel<<<(NCHUNK + 255) / 256, 256, 0, stream>>>(
            embed, latent, ws_emb, ws_lat);
        dim3 grid(SK / NT, SS / MT, BB);
        neg_loss_main<<<grid, dim3(256), 0, stream>>>(
            ws_lat, labels, samples, ws_emb, out);
    } else {
        dim3 grid(SK / 64, SS / 64, BB);
        neg_loss_fallback<<<grid, dim3(256), 0, stream>>>(
            latent, labels, samples, embed, out);
    }
}

// Round 3
// 42.716 us; speedup vs baseline: 2.1859x; 2.1792x over previous
//
#include <hip/hip_runtime.h>
#include <hip/hip_bf16.h>
#include <math.h>

#define BB 32
#define SS 256
#define DD 128
#define KK 16
#define VV 50000
#define SK (SS*KK)   // 4096

typedef __attribute__((ext_vector_type(8))) short bf16x8;
typedef __attribute__((ext_vector_type(4))) float f32x4;
typedef unsigned short ushort_t;

static __device__ __forceinline__ short f2bf(float f) {
    unsigned u = __float_as_uint(f);
    unsigned r = (u + 0x7fffu + ((u >> 16) & 1u)) >> 16;
    return (short)r;
}

// byte offset of element (row, d) in a [R][128] bf16 LDS tile, XOR-swizzled
// (16B chunk index q -> q ^ (row&7))
static __device__ __forceinline__ int lds_off(int row, int d) {
    return row * 256 + ((d * 2) ^ ((row & 7) << 4));
}

static __device__ __forceinline__ void gload_lds16(const void* g, void* lds) {
    __builtin_amdgcn_global_load_lds(
        (const __attribute__((address_space(1))) unsigned int*)g,
        (__attribute__((address_space(3))) unsigned int*)lds, 16, 0, 0);
}

// ---------------- convert kernel: fp32 -> bf16 (embed then latent) ----------
#define NEMB (VV*DD)          // 6,400,000
#define NLAT (BB*SS*DD)       // 1,048,576
#define NCHUNK ((NEMB+NLAT)/8)

__global__ __launch_bounds__(256)
void convert_kernel(const float* __restrict__ embed,
                    const float* __restrict__ latent,
                    ushort_t* __restrict__ ws_emb,
                    ushort_t* __restrict__ ws_lat)
{
    int i = blockIdx.x * 256 + threadIdx.x;
    if (i >= NCHUNK) return;
    const float* src;
    ushort_t* dst;
    if (i < NEMB / 8) {
        src = embed + (size_t)i * 8;
        dst = ws_emb + (size_t)i * 8;
    } else {
        int k = i - NEMB / 8;
        src = latent + (size_t)k * 8;
        dst = ws_lat + (size_t)k * 8;
    }
    float f[8];
    *(float4*)(f + 0) = ((const float4*)src)[0];
    *(float4*)(f + 4) = ((const float4*)src)[1];
    short o[8];
    #pragma unroll
    for (int e = 0; e < 8; ++e) o[e] = f2bf(f[e]);
    *(bf16x8*)dst = *(bf16x8*)o;
}

// ---------------- main kernel: 64x128 tile, bf16 inputs via ws --------------
#define MT 64
#define NT 128

__global__ __launch_bounds__(256)
void neg_loss_main(const ushort_t* __restrict__ lat_bf,   // [B,S,D] bf16
                   const int*      __restrict__ labels,   // [B,S]
                   const int*      __restrict__ samples,  // [B,S*(K-1)]
                   const ushort_t* __restrict__ emb_bf,   // [V,D] bf16
                   float* __restrict__ out)               // [B,S,S]
{
    __shared__ char ldsA[MT * 256];   // 16 KB
    __shared__ char ldsB[NT * 256];   // 32 KB

    const int b    = blockIdx.z;
    const int m0   = blockIdx.y * MT;
    const int n0   = blockIdx.x * NT;
    const int tid  = threadIdx.x;
    const int wave = tid >> 6;
    const int lane = tid & 63;
    const int q    = lane & 15;
    const int sub  = lane >> 4;   // 0..3

    // ---- stage A: 64 latent rows (bf16), src pre-swizzled, LDS linear ----
    #pragma unroll
    for (int t = 0; t < 4; ++t) {
        const int r0 = wave * 16 + t * 4;
        const int r  = r0 + sub;
        const ushort_t* src = lat_bf + ((size_t)(b * SS + m0 + r) * DD)
                                     + ((q ^ (r & 7)) << 3);
        gload_lds16(src, ldsA + r0 * 256);
    }

    // ---- stage B: 128 gathered embedding rows (bf16) ----
    #pragma unroll
    for (int t = 0; t < 8; ++t) {
        const int c0 = wave * 32 + t * 4;
        const int c  = c0 + sub;
        const int gc = n0 + c;
        const int j  = gc >> 4;
        const int k  = gc & 15;
        const int idx = (k < 15)
            ? samples[(size_t)b * (SS * (KK - 1)) + j * (KK - 1) + k]
            : labels[b * SS + j];
        const ushort_t* src = emb_bf + (size_t)idx * DD + ((q ^ (c & 7)) << 3);
        gload_lds16(src, ldsB + c0 * 256);
    }

    __syncthreads();

    // ---- MFMA: wave w computes i rows 0..63 x candidate cols [w*32, w*32+32)
    //      SWAPPED operands: D[row=candidate][col=latent_row] so the K=16
    //      softmax group lies along the register/sub axis (in-lane + 2 shfl).
    const int lr = lane & 15;
    const int lk = (lane >> 4) * 8;

    f32x4 acc[4][2] = {};
    #pragma unroll
    for (int ks = 0; ks < 4; ++ks) {
        const int d = ks * 32 + lk;
        bf16x8 a[4], bv[2];
        #pragma unroll
        for (int mf = 0; mf < 4; ++mf)
            a[mf] = *(const bf16x8*)(ldsA + lds_off(mf * 16 + lr, d));
        #pragma unroll
        for (int nf = 0; nf < 2; ++nf)
            bv[nf] = *(const bf16x8*)(ldsB + lds_off(wave * 32 + nf * 16 + lr, d));
        #pragma unroll
        for (int mf = 0; mf < 4; ++mf)
            #pragma unroll
            for (int nf = 0; nf < 2; ++nf)
                acc[mf][nf] = __builtin_amdgcn_mfma_f32_16x16x32_bf16(
                    bv[nf], a[mf], acc[mf][nf], 0, 0, 0);
    }

    // ---- fused LSE epilogue (swapped layout) ----
    // D[c][i]: i = lane&15 (global m0+mf*16+i), c-row = sub*4+reg = k of group
    #pragma unroll
    for (int mf = 0; mf < 4; ++mf) {
        #pragma unroll
        for (int nf = 0; nf < 2; ++nf) {
            const f32x4 v = acc[mf][nf];
            float mx = fmaxf(fmaxf(v[0], v[1]), fmaxf(v[2], v[3]));
            mx = fmaxf(mx, __shfl_xor(mx, 16));
            mx = fmaxf(mx, __shfl_xor(mx, 32));
            float e = __expf(v[0] - mx) + __expf(v[1] - mx)
                    + __expf(v[2] - mx) + __expf(v[3] - mx);
            e += __shfl_xor(e, 16);
            e += __shfl_xor(e, 32);
            float pos = __shfl(v[3], (lane & 15) | 48);   // k==15: sub=3, reg=3
            if (sub == 0) {
                const int i  = m0 + mf * 16 + (lane & 15);
                const int jj = (n0 >> 4) + wave * 2 + nf;
                out[((size_t)b * SS + i) * SS + jj] = pos - mx - __logf(e);
            }
        }
    }
}

// ---------------- fallback (R1 kernel, fp32 gather + in-kernel convert) -----
__global__ __launch_bounds__(256)
void neg_loss_fallback(const float* __restrict__ latent,
                       const int*   __restrict__ labels,
                       const int*   __restrict__ samples,
                       const float* __restrict__ embed,
                       float* __restrict__ out)
{
    __shared__ char ldsA[64 * 256];
    __shared__ char ldsB[64 * 256];

    const int b   = blockIdx.z;
    const int m0  = blockIdx.y * 64;
    const int n0  = blockIdx.x * 64;
    const int tid = threadIdx.x;

    {
        const int r  = tid >> 2;
        const int d0 = (tid & 3) * 32;
        const float* src = latent + ((size_t)b * SS + (m0 + r)) * DD + d0;
        float f[32];
        #pragma unroll
        for (int c = 0; c < 8; ++c)
            *(float4*)(f + 4 * c) = ((const float4*)src)[c];
        #pragma unroll
        for (int c = 0; c < 4; ++c) {
            short tmp[8];
            #pragma unroll
            for (int e = 0; e < 8; ++e) tmp[e] = f2bf(f[c * 8 + e]);
            *(bf16x8*)(ldsA + lds_off(r, d0 + c * 8)) = *(bf16x8*)tmp;
        }
    }
    {
        const int c   = tid >> 2;
        const int d0  = (tid & 3) * 32;
        const int col = n0 + c;
        const int j   = col >> 4;
        const int k   = col & 15;
        const int idx = (k < 15) ? samples[(size_t)b * (SS * (KK - 1)) + j * (KK - 1) + k]
                                 : labels[b * SS + j];
        const float* src = embed + (size_t)idx * DD + d0;
        float f[32];
        #pragma unroll
        for (int cc = 0; cc < 8; ++cc)
            *(float4*)(f + 4 * cc) = ((const float4*)src)[cc];
        #pragma unroll
        for (int cc = 0; cc < 4; ++cc) {
            short tmp[8];
            #pragma unroll
            for (int e = 0; e < 8; ++e) tmp[e] = f2bf(f[cc * 8 + e]);
            *(bf16x8*)(ldsB + lds_off(c, d0 + cc * 8)) = *(bf16x8*)tmp;
        }
    }
    __syncthreads();

    const int wave = tid >> 6;
    const int lane = tid & 63;
    const int wm = wave >> 1, wn = wave & 1;
    const int lr = lane & 15;
    const int lk = (lane >> 4) * 8;
    const int sub = lane >> 4;

    f32x4 acc[2][2] = {};
    #pragma unroll
    for (int ks = 0; ks < 4; ++ks) {
        const int d = ks * 32 + lk;
        bf16x8 a[2], bb2[2];
        #pragma unroll
        for (int mf = 0; mf < 2; ++mf)
            a[mf] = *(const bf16x8*)(ldsA + lds_off(wm * 32 + mf * 16 + lr, d));
        #pragma unroll
        for (int nf = 0; nf < 2; ++nf)
            bb2[nf] = *(const bf16x8*)(ldsB + lds_off(wn * 32 + nf * 16 + lr, d));
        #pragma unroll
        for (int mf = 0; mf < 2; ++mf)
            #pragma unroll
            for (int nf = 0; nf < 2; ++nf)
                acc[mf][nf] = __builtin_amdgcn_mfma_f32_16x16x32_bf16(
                    bb2[nf], a[mf], acc[mf][nf], 0, 0, 0);
    }

    #pragma unroll
    for (int mf = 0; mf < 2; ++mf) {
        #pragma unroll
        for (int nf = 0; nf < 2; ++nf) {
            const f32x4 v = acc[mf][nf];
            float mx = fmaxf(fmaxf(v[0], v[1]), fmaxf(v[2], v[3]));
            mx = fmaxf(mx, __shfl_xor(mx, 16));
            mx = fmaxf(mx, __shfl_xor(mx, 32));
            float e = __expf(v[0] - mx) + __expf(v[1] - mx)
                    + __expf(v[2] - mx) + __expf(v[3] - mx);
            e += __shfl_xor(e, 16);
            e += __shfl_xor(e, 32);
            float pos = __shfl(v[3], (lane & 15) | 48);
            if (sub == 0) {
                const int i  = m0 + wm * 32 + mf * 16 + (lane & 15);
                const int jj = (n0 >> 4) + wn * 2 + nf;
                out[((size_t)b * SS + i) * SS + jj] = pos - mx - __logf(e);
            }
        }
    }
}

extern "C" void kernel_launch(void* const* d_in, const int* in_sizes, int n_in,
                              void* d_out, int out_size, void* d_ws, size_t ws_size,
                              hipStream_t stream) {
    const float* latent  = (const float*)d_in[0];
    const int*   labels  = (const int*)d_in[1];
    const int*   samples = (const int*)d_in[2];
    const float* embed   = (const float*)d_in[3];
    float* out = (float*)d_out;

    const size_t ws_needed = (size_t)(NEMB + NLAT) * 2;
    if (ws_size >= ws_needed) {
        ushort_t* ws_emb = (ushort_t*)d_ws;
        ushort_t* ws_lat = ws_emb + NEMB;
        convert_kernel<<<(NCHUNK + 255) / 256, 256, 0, stream>>>(
            embed, latent, ws_emb, ws_lat);
        dim3 grid(SK / NT, SS / MT, BB);
        neg_loss_main<<<grid, dim3(256), 0, stream>>>(
            ws_lat, labels, samples, ws_emb, out);
    } else {
        dim3 grid(SK / 64, SS / 64, BB);
        neg_loss_fallback<<<grid, dim3(256), 0, stream>>>(
            latent, labels, samples, embed, out);
    }
}